// Round 1
// baseline (3559.018 us; speedup 1.0000x reference)
//
#include <hip/hip_runtime.h>
#include <hip/hip_bf16.h>
#include <math.h>

// ---------------------------------------------------------------------------
// EpisodicMemory: cosine top-32 retrieval, B=256, N=500000, D=128.
// Pipeline: prep (norms/mask/qn) -> bf16 MFMA screen (threshold 0.19, index
// append) -> fallback full-scan safety net -> exact fp32 rescore + top-32
// select (tie-break: value desc, index asc == jax.lax.top_k) + gather.
// ws needed ~19 MB. Assumes Gaussian-sim data: true 32nd value ~0.31 >> 0.19.
// ---------------------------------------------------------------------------

#define D      128
#define KSEL   32
#define CAP    16384      // candidate capacity per query
#define THRESH 0.19f      // screen threshold (margin ~0.11 vs bf16 err ~1e-3)
#define EPSN   1e-8f

typedef __attribute__((ext_vector_type(8))) short bf16x8;  // 8 bf16 (4 VGPRs)
typedef __attribute__((ext_vector_type(4))) float f32x4;   // MFMA accumulator

__device__ inline unsigned short f2bf(float f) {   // fp32 -> bf16 (RNE)
    unsigned int u = __float_as_uint(f);
    u += 0x7FFFu + ((u >> 16) & 1u);
    return (unsigned short)(u >> 16);
}

// --- 1. per-episode clamped norms + global valid count ----------------------
__global__ __launch_bounds__(256) void prep_keys(
    const float* __restrict__ keys, const float* __restrict__ sr,
    float* __restrict__ nrm, int* __restrict__ validCount, int N) {
    int t = threadIdx.x;
    int sub = t & 31;        // float4 slot within row (32*4 = 128 floats)
    int rsub = t >> 5;       // 8 rows per iteration
    for (int it = 0; it < 8; ++it) {
        int r = blockIdx.x * 64 + it * 8 + rsub;
        if (r >= N) break;
        float4 v = *(const float4*)(keys + (size_t)r * D + sub * 4);
        float ss = v.x * v.x + v.y * v.y + v.z * v.z + v.w * v.w;
        #pragma unroll
        for (int m = 1; m < 32; m <<= 1) ss += __shfl_xor(ss, m);
        if (sub == 0) {
            nrm[r] = fmaxf(sqrtf(ss), EPSN);      // store clamped NORM
            if (sr[r] >= 0.7f) atomicAdd(validCount, 1);
        }
    }
}

// --- 2. query normalize: qn (fp32, exact divide) + qnb (bf16) ---------------
__global__ __launch_bounds__(128) void prep_q(
    const float* __restrict__ query, float* __restrict__ qn,
    unsigned short* __restrict__ qnb) {
    __shared__ float red[2];
    int b = blockIdx.x, k = threadIdx.x;
    float v = query[b * D + k];
    float ss = v * v;
    #pragma unroll
    for (int m = 1; m < 64; m <<= 1) ss += __shfl_xor(ss, m);
    if ((k & 63) == 0) red[k >> 6] = ss;
    __syncthreads();
    float den = fmaxf(sqrtf(red[0] + red[1]), EPSN);
    float q = v / den;                 // divide (mirror reference rounding)
    qn[b * D + k] = q;
    qnb[b * D + k] = f2bf(q);
}

// --- 3. apply success mask: masked rows get norm=INF (k/INF == 0 == sim*0) --
__global__ __launch_bounds__(256) void finalize_mask(
    const float* __restrict__ sr, float* __restrict__ nrm,
    const int* __restrict__ validCount, int N) {
    int n = blockIdx.x * blockDim.x + threadIdx.x;
    if (n >= N) return;
    int any = *validCount;
    if (!(sr[n] >= 0.7f || any == 0)) nrm[n] = INFINITY;
}

// --- 4. bf16 MFMA screen: append episode idx where approx sim >= THRESH -----
#define KB_STRIDE 136   // 128 + 8 bf16 pad -> B-frag ds_read is 2-way (free)
__global__ __launch_bounds__(256) void screen(
    const float* __restrict__ keys, const float* __restrict__ nrm,
    const unsigned short* __restrict__ qnb,
    int* __restrict__ candCount, int* __restrict__ candIdx, int N, int B) {
    __shared__ unsigned short kb[64 * KB_STRIDE];   // 64 episodes x 128 bf16
    int t = threadIdx.x;
    int n0 = blockIdx.x * 64;
    // stage: coalesced fp32 read, scale by 1/norm (0 for masked/tail), cvt bf16
    {
        int f4i = t & 31;
        int esub = t >> 5;
        #pragma unroll
        for (int it = 0; it < 8; ++it) {
            int e = it * 8 + esub;
            int n = n0 + e;
            float4 v = make_float4(0.f, 0.f, 0.f, 0.f);
            float scale = 0.f;
            if (n < N) {
                v = *(const float4*)(keys + (size_t)n * D + f4i * 4);
                scale = 1.f / nrm[n];              // INF -> 0 (masked)
            }
            unsigned short* dst = kb + e * KB_STRIDE + f4i * 4;
            dst[0] = f2bf(v.x * scale); dst[1] = f2bf(v.y * scale);
            dst[2] = f2bf(v.z * scale); dst[3] = f2bf(v.w * scale);
        }
    }
    __syncthreads();
    int lane = t & 63, wave = t >> 6;
    int col = lane & 15, quad = lane >> 4;
    int eb = wave * 16;                            // 4 waves x 16 episodes
    // B-frags (episodes) loaded once, reused across all 16 query tiles
    bf16x8 bfr[4];
    #pragma unroll
    for (int kk = 0; kk < 4; ++kk)
        bfr[kk] = *(const bf16x8*)(kb + (eb + col) * KB_STRIDE + kk * 32 + quad * 8);
    int eg = n0 + eb + col;
    for (int qt = 0; qt < (B >> 4); ++qt) {
        f32x4 acc = {0.f, 0.f, 0.f, 0.f};
        #pragma unroll
        for (int kk = 0; kk < 4; ++kk) {
            // A frag: A[m=lane&15][k=quad*8+j], contiguous in k (L1/L2-hot)
            bf16x8 a = *(const bf16x8*)(qnb + (size_t)(qt * 16 + col) * D + kk * 32 + quad * 8);
            acc = __builtin_amdgcn_mfma_f32_16x16x32_bf16(a, bfr[kk], acc, 0, 0, 0);
        }
        #pragma unroll
        for (int r = 0; r < 4; ++r) {             // D: row=quad*4+r (query), col (episode)
            if (acc[r] >= THRESH) {
                int q = qt * 16 + quad * 4 + r;
                int pos = atomicAdd(&candCount[q], 1);
                if (pos < CAP) candIdx[(size_t)q * CAP + pos] = eg;
            }
        }
    }
}

// --- 5. safety net: exact full rescan iff count anomalous (never on data) ---
__global__ __launch_bounds__(256) void fallback_scan(
    const float* __restrict__ keys, const float* __restrict__ nrm,
    const float* __restrict__ qn, int* __restrict__ candCount,
    int* __restrict__ candIdx, int N) {
    int b = blockIdx.x;
    int cnt = candCount[b];
    if (cnt >= KSEL && cnt <= CAP) return;
    __shared__ float qs[D];
    int t = threadIdx.x;
    if (t < D) qs[t] = qn[b * D + t];
    __syncthreads();
    int*   myI = candIdx + (size_t)b * CAP + t * 32;          // global scratch
    float* myV = (float*)(candIdx + (size_t)b * CAP + 8192) + t * 32;
    for (int j = 0; j < 32; ++j) { myV[j] = -1e30f; myI[j] = 0; }
    float minv = -1e30f; int mins = 0;
    for (int n = t; n < N; n += 256) {
        float m = nrm[n];
        const float4* kp = (const float4*)(keys + (size_t)n * D);
        float s = 0.f;
        #pragma unroll
        for (int j = 0; j < 32; ++j) {
            float4 kv = kp[j];
            s += qs[j*4+0] * (kv.x / m) + qs[j*4+1] * (kv.y / m)
               + qs[j*4+2] * (kv.z / m) + qs[j*4+3] * (kv.w / m);
        }
        if (s > minv) {
            myV[mins] = s; myI[mins] = n;
            minv = myV[0]; mins = 0;
            for (int j = 1; j < 32; ++j) {
                float v = myV[j];
                if (v < minv) { minv = v; mins = j; }
            }
        }
    }
    __syncthreads();
    if (t == 0) candCount[b] = 256 * 32;
}

// --- 6. exact rescore + top-32 select + gather ------------------------------
// 192 threads: per-thread top-32 lists fit static LDS (<64 KB).
__global__ __launch_bounds__(192) void select_gather(
    const float* __restrict__ keys, const float* __restrict__ values,
    const float* __restrict__ sr, const float* __restrict__ nrm,
    const float* __restrict__ qn, const int* __restrict__ candCount,
    const int* __restrict__ candIdx,
    float* __restrict__ outK, float* __restrict__ outV,
    float* __restrict__ outS, int N) {
    __shared__ float qs[D];
    __shared__ float tv[192 * 32];
    __shared__ int   ti[192 * 32];
    __shared__ float redV[192];
    __shared__ int   redI[192];
    __shared__ int   wIdx[KSEL];
    int b = blockIdx.x, t = threadIdx.x;
    if (t < D) qs[t] = qn[b * D + t];
    float* myV = tv + t * 32;
    int*   myI = ti + t * 32;
    for (int j = 0; j < 32; ++j) { myV[j] = -1e30f; myI[j] = -1; }
    __syncthreads();
    int cnt = candCount[b];
    if (cnt > CAP) cnt = CAP;   // fallback rewrote these cases to 8192 anyway
    float minv = -1e30f; int mins = 0;
    for (int c = t; c < cnt; c += 192) {
        int n = candIdx[(size_t)b * CAP + c];
        if ((unsigned)n >= (unsigned)N) continue;       // safety
        float m = nrm[n];
        const float4* kp = (const float4*)(keys + (size_t)n * D);
        float s = 0.f;
        #pragma unroll
        for (int j = 0; j < 32; ++j) {                  // exact: q * (k / norm)
            float4 kv = kp[j];
            s += qs[j*4+0] * (kv.x / m) + qs[j*4+1] * (kv.y / m)
               + qs[j*4+2] * (kv.z / m) + qs[j*4+3] * (kv.w / m);
        }
        if (s > minv) {
            myV[mins] = s; myI[mins] = n;
            minv = myV[0]; mins = 0;
            for (int j = 1; j < 32; ++j) {
                float v = myV[j];
                if (v < minv) { minv = v; mins = j; }
            }
        }
    }
    __syncthreads();
    // 32 rounds of block argmax; tie-break (value desc, index asc) = jax top_k
    for (int r = 0; r < KSEL; ++r) {
        float bv = -2e30f; int bi = 0x7fffffff;
        for (int j = 0; j < 32; ++j) {
            float v = myV[j]; int i = myI[j];
            if (v > bv || (v == bv && i < bi)) { bv = v; bi = i; }
        }
        redV[t] = bv; redI[t] = bi;
        __syncthreads();
        if (t < 64) {
            float v1 = redV[t + 64];  int i1 = redI[t + 64];
            if (v1 > bv || (v1 == bv && i1 < bi)) { bv = v1; bi = i1; }
            float v2 = redV[t + 128]; int i2 = redI[t + 128];
            if (v2 > bv || (v2 == bv && i2 < bi)) { bv = v2; bi = i2; }
            #pragma unroll
            for (int m = 32; m >= 1; m >>= 1) {
                float ov = __shfl_xor(bv, m); int oi = __shfl_xor(bi, m);
                if (ov > bv || (ov == bv && oi < bi)) { bv = ov; bi = oi; }
            }
            if (t == 0) wIdx[r] = bi;
        }
        __syncthreads();
        int w = wIdx[r];
        for (int j = 0; j < 32; ++j)
            if (myI[j] == w) myV[j] = -3e30f;           // retire winner
    }
    // gather (coalesced within each retrieved row)
    for (int i = t; i < KSEL * (D / 4); i += 192) {     // keys: 1024 float4
        int r = i >> 5, f = i & 31;
        float4 v = *(const float4*)(keys + (size_t)wIdx[r] * D + f * 4);
        *(float4*)(outK + ((size_t)b * KSEL + r) * D + f * 4) = v;
    }
    for (int i = t; i < KSEL * (2 * D / 4); i += 192) { // values: 2048 float4
        int r = i >> 6, f = i & 63;
        float4 v = *(const float4*)(values + (size_t)wIdx[r] * (2 * D) + f * 4);
        *(float4*)(outV + ((size_t)b * KSEL + r) * (2 * D) + f * 4) = v;
    }
    if (t < KSEL) outS[(size_t)b * KSEL + t] = sr[wIdx[t]];
}

// ---------------------------------------------------------------------------
extern "C" void kernel_launch(void* const* d_in, const int* in_sizes, int n_in,
                              void* d_out, int out_size, void* d_ws, size_t ws_size,
                              hipStream_t stream) {
    const float* query  = (const float*)d_in[0];
    const float* keys   = (const float*)d_in[1];
    const float* values = (const float*)d_in[2];
    const float* sr     = (const float*)d_in[3];
    // d_in[4] = top_k (device scalar) — fixed at 32 per the reference setup.
    const int B = in_sizes[0] / D;      // 256
    const int N = in_sizes[3];          // 500000

    char* ws = (char*)d_ws;
    size_t off = 0;
    int* counters = (int*)ws;                       off = 4096;   // [0]=valid, [1..B]=candCount
    float* qn = (float*)(ws + off);                 off += (size_t)B * D * 4;
    unsigned short* qnb = (unsigned short*)(ws + off); off += (size_t)B * D * 2;
    float* nrm = (float*)(ws + off);                off += (((size_t)N * 4 + 255) & ~(size_t)255);
    int* candIdx = (int*)(ws + off);                off += (size_t)B * CAP * 4;
    // total ws use ~19 MB

    hipMemsetAsync(counters, 0, (B + 1) * sizeof(int), stream);
    prep_keys<<<(N + 63) / 64, 256, 0, stream>>>(keys, sr, nrm, counters, N);
    prep_q<<<B, 128, 0, stream>>>(query, qn, qnb);
    finalize_mask<<<(N + 255) / 256, 256, 0, stream>>>(sr, nrm, counters, N);
    screen<<<(N + 63) / 64, 256, 0, stream>>>(keys, nrm, qnb, counters + 1, candIdx, N, B);
    fallback_scan<<<B, 256, 0, stream>>>(keys, nrm, qn, counters + 1, candIdx, N);
    float* outK = (float*)d_out;
    float* outV = outK + (size_t)B * KSEL * D;
    float* outS = outV + (size_t)B * KSEL * 2 * D;
    select_gather<<<B, 192, 0, stream>>>(keys, values, sr, nrm, qn,
                                         counters + 1, candIdx,
                                         outK, outV, outS, N);
}

// Round 2
// 1356.320 us; speedup vs baseline: 2.6240x; 2.6240x over previous
//
#include <hip/hip_runtime.h>
#include <hip/hip_bf16.h>
#include <math.h>

// ---------------------------------------------------------------------------
// EpisodicMemory: cosine top-32 retrieval, B=256, N=500000, D=128.
// R1: killed same-address atomic serialization.
//  - prep_keys (1457us, one-address atomicAdd x150K) deleted; norms fused
//    into screen via half-wave shfl reduce. Keys now read from HBM ONCE.
//  - any-valid flag via ballot + block flag + plain store (no RMW).
//  - candCount padded to 1 counter/cacheline (16-int stride).
// Pipeline: memset -> valid_any -> prep_q -> screen(fused norm+mask+MFMA,
// threshold 0.19, index append) -> fallback (safety, no-op on data) ->
// exact fp32 rescore + top-32 (jax tie-break) + gather.
// ---------------------------------------------------------------------------

#define D      128
#define KSEL   32
#define CAP    16384      // candidate capacity per query
#define CPAD   16         // candCount stride in ints (one cacheline each)
#define THRESH 0.19f      // screen threshold (margin ~0.11 vs bf16 err ~1e-3)
#define EPSN   1e-8f

typedef __attribute__((ext_vector_type(8))) short bf16x8;  // 8 bf16 (4 VGPRs)
typedef __attribute__((ext_vector_type(4))) float f32x4;   // MFMA accumulator

__device__ inline unsigned short f2bf(float f) {   // fp32 -> bf16 (RNE)
    unsigned int u = __float_as_uint(f);
    u += 0x7FFFu + ((u >> 16) & 1u);
    return (unsigned short)(u >> 16);
}

// --- 1. any(sr >= 0.7)? ballot -> block flag -> plain store (no atomics) ----
__global__ __launch_bounds__(256) void valid_any(
    const float* __restrict__ sr, int* __restrict__ flag, int N) {
    __shared__ int any;
    if (threadIdx.x == 0) any = 0;
    __syncthreads();
    int i = blockIdx.x * 256 + threadIdx.x;
    bool v = (i < N) && (sr[i] >= 0.7f);
    if (__ballot(v) && (threadIdx.x & 63) == 0) any = 1;
    __syncthreads();
    if (threadIdx.x == 0 && any) *(volatile int*)flag = 1;  // benign race, same value
}

// --- 2. query normalize: qn (fp32, exact divide) + qnb (bf16) ---------------
__global__ __launch_bounds__(128) void prep_q(
    const float* __restrict__ query, float* __restrict__ qn,
    unsigned short* __restrict__ qnb) {
    __shared__ float red[2];
    int b = blockIdx.x, k = threadIdx.x;
    float v = query[b * D + k];
    float ss = v * v;
    #pragma unroll
    for (int m = 1; m < 64; m <<= 1) ss += __shfl_xor(ss, m);
    if ((k & 63) == 0) red[k >> 6] = ss;
    __syncthreads();
    float den = fmaxf(sqrtf(red[0] + red[1]), EPSN);
    float q = v / den;                 // divide (mirror reference rounding)
    qn[b * D + k] = q;
    qnb[b * D + k] = f2bf(q);
}

// --- 3. fused screen: norms + mask + bf16 MFMA + candidate append -----------
// Row e is staged by a contiguous 32-lane half-wave -> shfl row-norm for free.
// Writes masked nrm[] (INF for masked rows) for the exact rescore stage.
#define KB_STRIDE 136   // 128 + 8 bf16 pad
__global__ __launch_bounds__(256) void screen(
    const float* __restrict__ keys, const float* __restrict__ sr,
    const int* __restrict__ anyValid, float* __restrict__ nrm,
    const unsigned short* __restrict__ qnb,
    int* __restrict__ candCount, int* __restrict__ candIdx, int N, int B) {
    __shared__ unsigned short kb[64 * KB_STRIDE];   // 64 episodes x 128 bf16
    int t = threadIdx.x;
    int n0 = blockIdx.x * 64;
    int noneValid = (*anyValid == 0);
    {
        int f4i = t & 31;        // float4 slot within row
        int esub = t >> 5;       // 8 rows per iteration
        #pragma unroll
        for (int it = 0; it < 8; ++it) {
            int e = it * 8 + esub;
            int n = n0 + e;
            float4 v = make_float4(0.f, 0.f, 0.f, 0.f);
            bool inb = (n < N);
            if (inb) v = *(const float4*)(keys + (size_t)n * D + f4i * 4);
            float ss = v.x * v.x + v.y * v.y + v.z * v.z + v.w * v.w;
            #pragma unroll
            for (int m = 1; m < 32; m <<= 1) ss += __shfl_xor(ss, m);  // half-wave
            float norm = fmaxf(sqrtf(ss), EPSN);
            float scale = 0.f;
            if (inb) {
                bool valid = (sr[n] >= 0.7f) || noneValid;
                if (f4i == 0) nrm[n] = valid ? norm : INFINITY;  // k/INF==0==sim*0
                scale = valid ? (1.f / norm) : 0.f;
            }
            unsigned short* dst = kb + e * KB_STRIDE + f4i * 4;
            dst[0] = f2bf(v.x * scale); dst[1] = f2bf(v.y * scale);
            dst[2] = f2bf(v.z * scale); dst[3] = f2bf(v.w * scale);
        }
    }
    __syncthreads();
    int lane = t & 63, wave = t >> 6;
    int col = lane & 15, quad = lane >> 4;
    int eb = wave * 16;                            // 4 waves x 16 episodes
    // B-frags (episodes) loaded once, reused across all 16 query tiles
    bf16x8 bfr[4];
    #pragma unroll
    for (int kk = 0; kk < 4; ++kk)
        bfr[kk] = *(const bf16x8*)(kb + (eb + col) * KB_STRIDE + kk * 32 + quad * 8);
    int eg = n0 + eb + col;
    for (int qt = 0; qt < (B >> 4); ++qt) {
        f32x4 acc = {0.f, 0.f, 0.f, 0.f};
        #pragma unroll
        for (int kk = 0; kk < 4; ++kk) {
            // A frag: A[m=lane&15][k=quad*8+j], contiguous in k (L1/L2-hot)
            bf16x8 a = *(const bf16x8*)(qnb + (size_t)(qt * 16 + col) * D + kk * 32 + quad * 8);
            acc = __builtin_amdgcn_mfma_f32_16x16x32_bf16(a, bfr[kk], acc, 0, 0, 0);
        }
        #pragma unroll
        for (int r = 0; r < 4; ++r) {             // D: row=quad*4+r (query), col (episode)
            if (acc[r] >= THRESH) {
                int q = qt * 16 + quad * 4 + r;
                int pos = atomicAdd(&candCount[q * CPAD], 1);
                if (pos < CAP) candIdx[(size_t)q * CAP + pos] = eg;
            }
        }
    }
}

// --- 4. safety net: exact full rescan iff count anomalous (never on data) ---
__global__ __launch_bounds__(256) void fallback_scan(
    const float* __restrict__ keys, const float* __restrict__ nrm,
    const float* __restrict__ qn, int* __restrict__ candCount,
    int* __restrict__ candIdx, int N) {
    int b = blockIdx.x;
    int cnt = candCount[b * CPAD];
    if (cnt >= KSEL && cnt <= CAP) return;
    __shared__ float qs[D];
    int t = threadIdx.x;
    if (t < D) qs[t] = qn[b * D + t];
    __syncthreads();
    int*   myI = candIdx + (size_t)b * CAP + t * 32;          // global scratch
    float* myV = (float*)(candIdx + (size_t)b * CAP + 8192) + t * 32;
    for (int j = 0; j < 32; ++j) { myV[j] = -1e30f; myI[j] = 0; }
    float minv = -1e30f; int mins = 0;
    for (int n = t; n < N; n += 256) {
        float m = nrm[n];                                     // INF if masked
        const float4* kp = (const float4*)(keys + (size_t)n * D);
        float s = 0.f;
        #pragma unroll
        for (int j = 0; j < 32; ++j) {
            float4 kv = kp[j];
            s += qs[j*4+0] * (kv.x / m) + qs[j*4+1] * (kv.y / m)
               + qs[j*4+2] * (kv.z / m) + qs[j*4+3] * (kv.w / m);
        }
        if (s > minv) {
            myV[mins] = s; myI[mins] = n;
            minv = myV[0]; mins = 0;
            for (int j = 1; j < 32; ++j) {
                float v = myV[j];
                if (v < minv) { minv = v; mins = j; }
            }
        }
    }
    __syncthreads();
    if (t == 0) candCount[b * CPAD] = 256 * 32;
}

// --- 5. exact rescore + top-32 select + gather ------------------------------
// 192 threads: per-thread top-32 lists fit static LDS (<64 KB).
__global__ __launch_bounds__(192) void select_gather(
    const float* __restrict__ keys, const float* __restrict__ values,
    const float* __restrict__ sr, const float* __restrict__ nrm,
    const float* __restrict__ qn, const int* __restrict__ candCount,
    const int* __restrict__ candIdx,
    float* __restrict__ outK, float* __restrict__ outV,
    float* __restrict__ outS, int N) {
    __shared__ float qs[D];
    __shared__ float tv[192 * 32];
    __shared__ int   ti[192 * 32];
    __shared__ float redV[192];
    __shared__ int   redI[192];
    __shared__ int   wIdx[KSEL];
    int b = blockIdx.x, t = threadIdx.x;
    if (t < D) qs[t] = qn[b * D + t];
    float* myV = tv + t * 32;
    int*   myI = ti + t * 32;
    for (int j = 0; j < 32; ++j) { myV[j] = -1e30f; myI[j] = -1; }
    __syncthreads();
    int cnt = candCount[b * CPAD];
    if (cnt > CAP) cnt = CAP;   // fallback rewrote anomalous cases to 8192
    float minv = -1e30f; int mins = 0;
    for (int c = t; c < cnt; c += 192) {
        int n = candIdx[(size_t)b * CAP + c];
        if ((unsigned)n >= (unsigned)N) continue;       // safety
        float m = nrm[n];
        const float4* kp = (const float4*)(keys + (size_t)n * D);
        float s = 0.f;
        #pragma unroll
        for (int j = 0; j < 32; ++j) {                  // exact: q * (k / norm)
            float4 kv = kp[j];
            s += qs[j*4+0] * (kv.x / m) + qs[j*4+1] * (kv.y / m)
               + qs[j*4+2] * (kv.z / m) + qs[j*4+3] * (kv.w / m);
        }
        if (s > minv) {
            myV[mins] = s; myI[mins] = n;
            minv = myV[0]; mins = 0;
            for (int j = 1; j < 32; ++j) {
                float v = myV[j];
                if (v < minv) { minv = v; mins = j; }
            }
        }
    }
    __syncthreads();
    // 32 rounds of block argmax; tie-break (value desc, index asc) = jax top_k
    for (int r = 0; r < KSEL; ++r) {
        float bv = -2e30f; int bi = 0x7fffffff;
        for (int j = 0; j < 32; ++j) {
            float v = myV[j]; int i = myI[j];
            if (v > bv || (v == bv && i < bi)) { bv = v; bi = i; }
        }
        redV[t] = bv; redI[t] = bi;
        __syncthreads();
        if (t < 64) {
            float v1 = redV[t + 64];  int i1 = redI[t + 64];
            if (v1 > bv || (v1 == bv && i1 < bi)) { bv = v1; bi = i1; }
            float v2 = redV[t + 128]; int i2 = redI[t + 128];
            if (v2 > bv || (v2 == bv && i2 < bi)) { bv = v2; bi = i2; }
            #pragma unroll
            for (int m = 32; m >= 1; m >>= 1) {
                float ov = __shfl_xor(bv, m); int oi = __shfl_xor(bi, m);
                if (ov > bv || (ov == bv && oi < bi)) { bv = ov; bi = oi; }
            }
            if (t == 0) wIdx[r] = bi;
        }
        __syncthreads();
        int w = wIdx[r];
        for (int j = 0; j < 32; ++j)
            if (myI[j] == w) myV[j] = -3e30f;           // retire winner
    }
    // gather (coalesced within each retrieved row)
    for (int i = t; i < KSEL * (D / 4); i += 192) {     // keys: 1024 float4
        int r = i >> 5, f = i & 31;
        float4 v = *(const float4*)(keys + (size_t)wIdx[r] * D + f * 4);
        *(float4*)(outK + ((size_t)b * KSEL + r) * D + f * 4) = v;
    }
    for (int i = t; i < KSEL * (2 * D / 4); i += 192) { // values: 2048 float4
        int r = i >> 6, f = i & 63;
        float4 v = *(const float4*)(values + (size_t)wIdx[r] * (2 * D) + f * 4);
        *(float4*)(outV + ((size_t)b * KSEL + r) * (2 * D) + f * 4) = v;
    }
    if (t < KSEL) outS[(size_t)b * KSEL + t] = sr[wIdx[t]];
}

// ---------------------------------------------------------------------------
extern "C" void kernel_launch(void* const* d_in, const int* in_sizes, int n_in,
                              void* d_out, int out_size, void* d_ws, size_t ws_size,
                              hipStream_t stream) {
    const float* query  = (const float*)d_in[0];
    const float* keys   = (const float*)d_in[1];
    const float* values = (const float*)d_in[2];
    const float* sr     = (const float*)d_in[3];
    // d_in[4] = top_k (device scalar) — fixed at 32 per the reference setup.
    const int B = in_sizes[0] / D;      // 256
    const int N = in_sizes[3];          // 500000

    char* ws = (char*)d_ws;
    size_t off = 0;
    int* anyFlag = (int*)ws;                        // [0] = any-valid flag
    int* candCnt = (int*)(ws + 64);                 // B counters, CPAD stride
    off = 64 + (size_t)B * CPAD * 4 + 4032;         // pad to 4 KB boundary-ish
    float* qn = (float*)(ws + off);                 off += (size_t)B * D * 4;
    unsigned short* qnb = (unsigned short*)(ws + off); off += (size_t)B * D * 2;
    float* nrm = (float*)(ws + off);                off += (((size_t)N * 4 + 255) & ~(size_t)255);
    int* candIdx = (int*)(ws + off);                off += (size_t)B * CAP * 4;
    // total ws use ~18.3 MB

    hipMemsetAsync(ws, 0, 64 + (size_t)B * CPAD * 4, stream);
    valid_any<<<(N + 255) / 256, 256, 0, stream>>>(sr, anyFlag, N);
    prep_q<<<B, 128, 0, stream>>>(query, qn, qnb);
    screen<<<(N + 63) / 64, 256, 0, stream>>>(keys, sr, anyFlag, nrm, qnb,
                                              candCnt, candIdx, N, B);
    fallback_scan<<<B, 256, 0, stream>>>(keys, nrm, qn, candCnt, candIdx, N);
    float* outK = (float*)d_out;
    float* outV = outK + (size_t)B * KSEL * D;
    float* outS = outV + (size_t)B * KSEL * 2 * D;
    select_gather<<<B, 192, 0, stream>>>(keys, values, sr, nrm, qn,
                                         candCnt, candIdx,
                                         outK, outV, outS, N);
}

// Round 3
// 1267.505 us; speedup vs baseline: 2.8079x; 1.0701x over previous
//
#include <hip/hip_runtime.h>
#include <hip/hip_bf16.h>
#include <math.h>

// ---------------------------------------------------------------------------
// EpisodicMemory: cosine top-32 retrieval, B=256, N=500000, D=128.
// R2: select_gather rebuilt — flat LDS score array (bank-conflict-free;
// R1 layout cost 1.5e8 conflict cycles), half-wave-per-candidate coalesced
// rescore, 32x block argmax. screen now skips key-row loads for invalid
// episodes (70% of N) -> keys HBM traffic 256MB -> ~77MB. CAP 16384->4096
// (35 sigma above expected 2370 candidates/query).
// ---------------------------------------------------------------------------

#define D      128
#define KSEL   32
#define CAP    4096       // candidate capacity per query (expected ~2370)
#define CPAD   16         // candCount stride in ints (one cacheline each)
#define THRESH 0.19f      // screen threshold (margin ~0.11 vs bf16 err ~1e-3)
#define EPSN   1e-8f

typedef __attribute__((ext_vector_type(8))) short bf16x8;  // 8 bf16 (4 VGPRs)
typedef __attribute__((ext_vector_type(4))) float f32x4;   // MFMA accumulator

__device__ inline unsigned short f2bf(float f) {   // fp32 -> bf16 (RNE)
    unsigned int u = __float_as_uint(f);
    u += 0x7FFFu + ((u >> 16) & 1u);
    return (unsigned short)(u >> 16);
}

// --- 1. any(sr >= 0.7)? ballot -> block flag -> plain store (no atomics) ----
__global__ __launch_bounds__(256) void valid_any(
    const float* __restrict__ sr, int* __restrict__ flag, int N) {
    __shared__ int any;
    if (threadIdx.x == 0) any = 0;
    __syncthreads();
    int i = blockIdx.x * 256 + threadIdx.x;
    bool v = (i < N) && (sr[i] >= 0.7f);
    if (__ballot(v) && (threadIdx.x & 63) == 0) any = 1;
    __syncthreads();
    if (threadIdx.x == 0 && any) *(volatile int*)flag = 1;  // benign race, same value
}

// --- 2. query normalize: qn (fp32, exact divide) + qnb (bf16) ---------------
__global__ __launch_bounds__(128) void prep_q(
    const float* __restrict__ query, float* __restrict__ qn,
    unsigned short* __restrict__ qnb) {
    __shared__ float red[2];
    int b = blockIdx.x, k = threadIdx.x;
    float v = query[b * D + k];
    float ss = v * v;
    #pragma unroll
    for (int m = 1; m < 64; m <<= 1) ss += __shfl_xor(ss, m);
    if ((k & 63) == 0) red[k >> 6] = ss;
    __syncthreads();
    float den = fmaxf(sqrtf(red[0] + red[1]), EPSN);
    float q = v / den;                 // divide (mirror reference rounding)
    qn[b * D + k] = q;
    qnb[b * D + k] = f2bf(q);
}

// --- 3. fused screen: norms + mask + bf16 MFMA + candidate append -----------
// Invalid episodes (sr<0.7, unless none valid): no key load, row = zeros,
// nrm = INF. Valid rows: half-wave coalesced load + shfl norm reduce.
#define KB_STRIDE 136   // 128 + 8 bf16 pad
__global__ __launch_bounds__(256) void screen(
    const float* __restrict__ keys, const float* __restrict__ sr,
    const int* __restrict__ anyValid, float* __restrict__ nrm,
    const unsigned short* __restrict__ qnb,
    int* __restrict__ candCount, int* __restrict__ candIdx, int N, int B) {
    __shared__ unsigned short kb[64 * KB_STRIDE];   // 64 episodes x 128 bf16
    int t = threadIdx.x;
    int n0 = blockIdx.x * 64;
    int noneValid = (*anyValid == 0);
    {
        int f4i = t & 31;        // float4 slot within row
        int esub = t >> 5;       // 8 rows per iteration
        #pragma unroll
        for (int it = 0; it < 8; ++it) {
            int e = it * 8 + esub;
            int n = n0 + e;
            bool inb = (n < N);
            bool valid = inb && ((sr[n] >= 0.7f) || noneValid);
            float4 v = make_float4(0.f, 0.f, 0.f, 0.f);
            if (valid) v = *(const float4*)(keys + (size_t)n * D + f4i * 4);
            float ss = v.x * v.x + v.y * v.y + v.z * v.z + v.w * v.w;
            #pragma unroll
            for (int m = 1; m < 32; m <<= 1) ss += __shfl_xor(ss, m);  // half-wave
            float norm = fmaxf(sqrtf(ss), EPSN);
            if (inb && f4i == 0) nrm[n] = valid ? norm : INFINITY;  // k/INF==0
            float scale = valid ? (1.f / norm) : 0.f;
            unsigned short* dst = kb + e * KB_STRIDE + f4i * 4;
            dst[0] = f2bf(v.x * scale); dst[1] = f2bf(v.y * scale);
            dst[2] = f2bf(v.z * scale); dst[3] = f2bf(v.w * scale);
        }
    }
    __syncthreads();
    int lane = t & 63, wave = t >> 6;
    int col = lane & 15, quad = lane >> 4;
    int eb = wave * 16;                            // 4 waves x 16 episodes
    // B-frags (episodes) loaded once, reused across all 16 query tiles
    bf16x8 bfr[4];
    #pragma unroll
    for (int kk = 0; kk < 4; ++kk)
        bfr[kk] = *(const bf16x8*)(kb + (eb + col) * KB_STRIDE + kk * 32 + quad * 8);
    int eg = n0 + eb + col;
    for (int qt = 0; qt < (B >> 4); ++qt) {
        f32x4 acc = {0.f, 0.f, 0.f, 0.f};
        #pragma unroll
        for (int kk = 0; kk < 4; ++kk) {
            // A frag: A[m=lane&15][k=quad*8+j], contiguous in k (L2-hot)
            bf16x8 a = *(const bf16x8*)(qnb + (size_t)(qt * 16 + col) * D + kk * 32 + quad * 8);
            acc = __builtin_amdgcn_mfma_f32_16x16x32_bf16(a, bfr[kk], acc, 0, 0, 0);
        }
        #pragma unroll
        for (int r = 0; r < 4; ++r) {             // D: row=quad*4+r (query), col (episode)
            if (acc[r] >= THRESH) {
                int q = qt * 16 + quad * 4 + r;
                int pos = atomicAdd(&candCount[q * CPAD], 1);
                if (pos < CAP) candIdx[(size_t)q * CAP + pos] = eg;
            }
        }
    }
}

// --- 4. safety net: exact full rescan iff count anomalous (never on data) ---
// 128 threads x top-32 each -> exactly CAP=4096 candidates for the rescorer.
__global__ __launch_bounds__(128) void fallback_scan(
    const float* __restrict__ keys, const float* __restrict__ nrm,
    const float* __restrict__ qn, int* __restrict__ candCount,
    int* __restrict__ candIdx, int N) {
    int b = blockIdx.x;
    int cnt = candCount[b * CPAD];
    if (cnt >= KSEL && cnt <= CAP) return;
    __shared__ float qs[D];
    __shared__ float tv[32 * 128];      // column-major [j*128 + t]: conflict-free
    __shared__ int   ti[32 * 128];
    int t = threadIdx.x;
    qs[t] = qn[b * D + t];
    __syncthreads();
    for (int j = 0; j < 32; ++j) { tv[j * 128 + t] = -1e30f; ti[j * 128 + t] = 0; }
    float minv = -1e30f; int mins = 0;
    for (int n = t; n < N; n += 128) {
        float m = nrm[n];                                     // INF if masked
        const float4* kp = (const float4*)(keys + (size_t)n * D);
        float s = 0.f;
        #pragma unroll
        for (int j = 0; j < 32; ++j) {
            float4 kv = kp[j];
            s += qs[j*4+0] * (kv.x / m) + qs[j*4+1] * (kv.y / m)
               + qs[j*4+2] * (kv.z / m) + qs[j*4+3] * (kv.w / m);
        }
        if (s > minv) {
            tv[mins * 128 + t] = s; ti[mins * 128 + t] = n;
            minv = tv[t]; mins = 0;
            for (int j = 1; j < 32; ++j) {
                float v = tv[j * 128 + t];
                if (v < minv) { minv = v; mins = j; }
            }
        }
    }
    __syncthreads();
    for (int j = 0; j < 32; ++j)
        candIdx[(size_t)b * CAP + t * 32 + j] = ti[j * 128 + t];
    if (t == 0) candCount[b * CPAD] = CAP;
}

// --- 5. exact rescore + top-32 select + gather ------------------------------
// Phase A: half-wave per candidate (coalesced 512B row), flat LDS sc/si.
// Phase B: 32 x block argmax over flat array (stride-1: conflict-free).
__global__ __launch_bounds__(256) void select_gather(
    const float* __restrict__ keys, const float* __restrict__ values,
    const float* __restrict__ sr, const float* __restrict__ nrm,
    const float* __restrict__ qn, const int* __restrict__ candCount,
    const int* __restrict__ candIdx,
    float* __restrict__ outK, float* __restrict__ outV,
    float* __restrict__ outS, int N) {
    __shared__ float qs[D];
    __shared__ float sc[CAP];           // 16 KB
    __shared__ int   si[CAP];           // 16 KB
    __shared__ float redV[4];
    __shared__ int   redI[4], redC[4];
    __shared__ int   wIdx[KSEL];
    int b = blockIdx.x, t = threadIdx.x;
    if (t < D) qs[t] = qn[b * D + t];
    __syncthreads();
    int cnt = candCount[b * CPAD];
    if (cnt > CAP) cnt = CAP;           // fallback rewrote anomalous cases
    // --- Phase A: exact rescore, one candidate per half-wave ---
    int hw = t >> 5, l = t & 31;        // 8 half-waves of 32 lanes
    float4 q4 = *(const float4*)(qs + l * 4);
    for (int c = hw; c < cnt; c += 8) {
        int n = candIdx[(size_t)b * CAP + c];
        if ((unsigned)n >= (unsigned)N) n = 0;              // safety
        float m = nrm[n];
        float4 kv = *(const float4*)(keys + (size_t)n * D + l * 4);
        float s = q4.x * (kv.x / m) + q4.y * (kv.y / m)
                + q4.z * (kv.z / m) + q4.w * (kv.w / m);    // exact: q*(k/norm)
        #pragma unroll
        for (int msk = 1; msk < 32; msk <<= 1) s += __shfl_xor(s, msk);
        if (l == 0) { sc[c] = s; si[c] = n; }
    }
    __syncthreads();
    // --- Phase B: 32 rounds block argmax; tie (v desc, n asc) = jax top_k ---
    for (int r = 0; r < KSEL; ++r) {
        float bv = -1e30f; int bi = 0x7fffffff, bc = -1;
        for (int c = t; c < cnt; c += 256) {
            float v = sc[c]; int n = si[c];
            if (v > bv || (v == bv && n < bi)) { bv = v; bi = n; bc = c; }
        }
        #pragma unroll
        for (int msk = 1; msk < 64; msk <<= 1) {
            float ov = __shfl_xor(bv, msk);
            int oi = __shfl_xor(bi, msk);
            int oc = __shfl_xor(bc, msk);
            if (ov > bv || (ov == bv && oi < bi)) { bv = ov; bi = oi; bc = oc; }
        }
        if ((t & 63) == 0) { redV[t >> 6] = bv; redI[t >> 6] = bi; redC[t >> 6] = bc; }
        __syncthreads();
        if (t == 0) {
            for (int w = 1; w < 4; ++w)
                if (redV[w] > bv || (redV[w] == bv && redI[w] < bi)) {
                    bv = redV[w]; bi = redI[w]; bc = redC[w];
                }
            wIdx[r] = ((unsigned)bi < (unsigned)N) ? bi : 0;
            if (bc >= 0) sc[bc] = -2e30f;                   // retire winner
        }
        __syncthreads();
    }
    // --- gather (coalesced 512B / 1KB rows) ---
    for (int i = t; i < KSEL * (D / 4); i += 256) {         // keys: 1024 float4
        int r = i >> 5, f = i & 31;
        float4 v = *(const float4*)(keys + (size_t)wIdx[r] * D + f * 4);
        *(float4*)(outK + ((size_t)b * KSEL + r) * D + f * 4) = v;
    }
    for (int i = t; i < KSEL * (2 * D / 4); i += 256) {     // values: 2048 float4
        int r = i >> 6, f = i & 63;
        float4 v = *(const float4*)(values + (size_t)wIdx[r] * (2 * D) + f * 4);
        *(float4*)(outV + ((size_t)b * KSEL + r) * (2 * D) + f * 4) = v;
    }
    if (t < KSEL) outS[(size_t)b * KSEL + t] = sr[wIdx[t]];
}

// ---------------------------------------------------------------------------
extern "C" void kernel_launch(void* const* d_in, const int* in_sizes, int n_in,
                              void* d_out, int out_size, void* d_ws, size_t ws_size,
                              hipStream_t stream) {
    const float* query  = (const float*)d_in[0];
    const float* keys   = (const float*)d_in[1];
    const float* values = (const float*)d_in[2];
    const float* sr     = (const float*)d_in[3];
    // d_in[4] = top_k (device scalar) — fixed at 32 per the reference setup.
    const int B = in_sizes[0] / D;      // 256
    const int N = in_sizes[3];          // 500000

    char* ws = (char*)d_ws;
    size_t off = 0;
    int* anyFlag = (int*)ws;                        // [0] = any-valid flag
    int* candCnt = (int*)(ws + 64);                 // B counters, CPAD stride
    off = 64 + (size_t)B * CPAD * 4 + 4032;         // ~16.5 KB header
    float* qn = (float*)(ws + off);                 off += (size_t)B * D * 4;
    unsigned short* qnb = (unsigned short*)(ws + off); off += (size_t)B * D * 2;
    float* nrm = (float*)(ws + off);                off += (((size_t)N * 4 + 255) & ~(size_t)255);
    int* candIdx = (int*)(ws + off);                off += (size_t)B * CAP * 4;
    // total ws use ~6.3 MB

    hipMemsetAsync(ws, 0, 64 + (size_t)B * CPAD * 4, stream);
    valid_any<<<(N + 255) / 256, 256, 0, stream>>>(sr, anyFlag, N);
    prep_q<<<B, 128, 0, stream>>>(query, qn, qnb);
    screen<<<(N + 63) / 64, 256, 0, stream>>>(keys, sr, anyFlag, nrm, qnb,
                                              candCnt, candIdx, N, B);
    fallback_scan<<<B, 128, 0, stream>>>(keys, nrm, qn, candCnt, candIdx, N);
    float* outK = (float*)d_out;
    float* outV = outK + (size_t)B * KSEL * D;
    float* outS = outV + (size_t)B * KSEL * 2 * D;
    select_gather<<<B, 256, 0, stream>>>(keys, values, sr, nrm, qn,
                                         candCnt, candIdx,
                                         outK, outV, outS, N);
}